// Round 5
// baseline (273.498 us; speedup 1.0000x reference)
//
#include <hip/hip_runtime.h>

// VectorQuantizer: inputs [8,4096,64] f32, weight [8192,64] f32.
// Outputs concat: quantized_st [2097152] f32, loss [1] f32, indices [32768] f32.
//
// R5: barrier-free MFMA argmin. B-fragments stream global->VGPR (L1/L2-resident
// packedW, 2MB), no LDS/__syncthreads in the K-loop. Epilogue packs c'=c+4>0
// into uint keys with 6-bit (g,t) id in the low mantissa bits; top-2 via
// umin/umax only. fp32 two-term bf16 split (hh + lh + hl GEMMs), then the
// proven np-exact recheck of rows with gap < MARGIN.

typedef short bf16x8 __attribute__((ext_vector_type(8)));
typedef float f32x4  __attribute__((ext_vector_type(4)));

#define N_ROWS 32768
#define DIM 64
#define K_CODES 8192
#define KSPLIT 8
#define KCHUNK 1024
#define OUT_Q 0
#define OUT_LOSS 2097152
#define OUT_IDX 2097153
#define MARGIN 2e-4f   // 1e-4 decision band + 6-bit truncation (3e-5) + slack
#define C_OFF 4.0f     // c' = c + 4 > 0 always (needs dot>2 => >9 sigma; never)

// ---- helpers ----
__device__ __forceinline__ unsigned f2u_ord(float f) {
    unsigned u = __float_as_uint(f);
    return (u & 0x80000000u) ? ~u : (u | 0x80000000u);
}
__device__ __forceinline__ float u2f_ord(unsigned u) {
    unsigned v = (u & 0x80000000u) ? (u & 0x7fffffffu) : ~u;
    return __uint_as_float(v);
}
__device__ __forceinline__ unsigned short bf16_rne(float f) {
    unsigned u = __float_as_uint(f);
    u += 0x7fffu + ((u >> 16) & 1u);
    return (unsigned short)(u >> 16);
}
__device__ __forceinline__ float bf16_to_f(unsigned short h) {
    return __uint_as_float(((unsigned)h) << 16);
}

// numpy pairwise_sum over 64 squared elements (exact np emulation)
__device__ __forceinline__ float np_pairwise_sq64(const float* v) {
    float r[8];
#pragma unroll
    for (int j = 0; j < 8; j++) r[j] = __fmul_rn(v[j], v[j]);
#pragma unroll
    for (int i = 8; i < 64; i += 8) {
#pragma unroll
        for (int j = 0; j < 8; j++)
            r[j] = __fadd_rn(r[j], __fmul_rn(v[i + j], v[i + j]));
    }
    return __fadd_rn(__fadd_rn(__fadd_rn(r[0], r[1]), __fadd_rn(r[2], r[3])),
                     __fadd_rn(__fadd_rn(r[4], r[5]), __fadd_rn(r[6], r[7])));
}

// ---------------- kernel 0: fused prep -------------------------------------
// Per block: 64 codes. Coalesced stage to LDS, then wsq (np-exact), wsqC
// (= wsq+4), and packedW B-fragments.
// packedW layout: [tile(512)][frag(4)][lane(64)] x int4;
// frag 0=hi_k0 1=hi_k32 2=lo_k0 3=lo_k32; B-frag lane holds
// B[k=(lane>>4)*8+j][n=lane&15] as bf16x8.
__global__ __launch_bounds__(256) void vq_prep(const float* __restrict__ weight,
                                               float* __restrict__ wsq,
                                               float* __restrict__ wsqC,
                                               int4* __restrict__ packedW) {
    __shared__ float sW[64 * 65];   // +1 pad per row
    int tid = threadIdx.x;
    int cbase = blockIdx.x * 64;

    // coalesced load: 64 codes x 64 dims = 1024 float4
    const float4* gw = (const float4*)(weight + (size_t)cbase * DIM);
#pragma unroll
    for (int i = 0; i < 4; i++) {
        int e = i * 256 + tid;            // float4 index within block slab
        float4 v = gw[e];
        int code = e >> 4, d4 = e & 15;
        float* dst = &sW[code * 65 + d4 * 4];
        dst[0] = v.x; dst[1] = v.y; dst[2] = v.z; dst[3] = v.w;
    }
    __syncthreads();

    if (tid < 64) {
        float s = np_pairwise_sq64(&sW[tid * 65]);
        wsq [cbase + tid] = s;
        wsqC[cbase + tid] = s + C_OFF;
    }

    int wave = tid >> 6, lane = tid & 63;
    int tile = blockIdx.x * 4 + wave;     // 0..511
    int codeL = wave * 16 + (lane & 15);
    int kq = (lane >> 4) * 8;
    const float* wp = &sW[codeL * 65];

    union { bf16x8 v; int4 q; } hi0, hi1, lo0, lo1;
#pragma unroll
    for (int j = 0; j < 8; j++) {
        float a = wp[kq + j];
        unsigned short ha = bf16_rne(a);
        hi0.v[j] = (short)ha;
        lo0.v[j] = (short)bf16_rne(a - bf16_to_f(ha));
        float b = wp[32 + kq + j];
        unsigned short hb = bf16_rne(b);
        hi1.v[j] = (short)hb;
        lo1.v[j] = (short)bf16_rne(b - bf16_to_f(hb));
    }
    size_t base = (size_t)tile * 4 * 64;
    packedW[base + 0 * 64 + lane] = hi0.q;
    packedW[base + 1 * 64 + lane] = hi1.q;
    packedW[base + 2 * 64 + lane] = lo0.q;
    packedW[base + 3 * 64 + lane] = lo1.q;
}

// ---------------- kernel 1: barrier-free MFMA argmin top-2 ------------------
// grid (256, KSPLIT) x 256. Block: 128 rows; wave: 32 rows. No LDS.
__global__ __launch_bounds__(256) void vq_argmin_mfma(const float* __restrict__ inp,
                                                      const int4* __restrict__ packedW,
                                                      const float* __restrict__ wsqC,
                                                      unsigned long long* __restrict__ bestk,
                                                      float* __restrict__ secd) {
    int wave = threadIdx.x >> 6;
    int lane = threadIdx.x & 63;
    int col  = lane & 15;
    int rbase = blockIdx.x * 128 + wave * 32;
    int kbase = blockIdx.y * KCHUNK;

    // A fragments: lane holds A[m=lane&15][k=(lane>>4)*8+j]
    int kq = (lane >> 4) * 8;
    bf16x8 ah[2][2], al[2][2];
#pragma unroll
    for (int rt = 0; rt < 2; rt++) {
        const float* xp = inp + (size_t)(rbase + rt * 16 + col) * DIM;
#pragma unroll
        for (int kc = 0; kc < 2; kc++) {
            const float4* xq = (const float4*)(xp + kc * 32 + kq);
            float4 a0 = xq[0], a1 = xq[1];
            float xe[8] = {a0.x, a0.y, a0.z, a0.w, a1.x, a1.y, a1.z, a1.w};
#pragma unroll
            for (int j = 0; j < 8; j++) {
                unsigned short h = bf16_rne(xe[j]);
                ah[rt][kc][j] = (short)h;
                al[rt][kc][j] = (short)bf16_rne(xe[j] - bf16_to_f(h));
            }
        }
    }

    unsigned best_u[8], sec_u[8];
#pragma unroll
    for (int s = 0; s < 8; s++) { best_u[s] = 0xFFFFFFFFu; sec_u[s] = 0xFFFFFFFFu; }

    const char* wb = (const char*)packedW + (size_t)kbase * 256;  // (kbase>>4)*4096
    const float* wq = wsqC + kbase + col;

    for (int g = 0; g < 16; g++) {
#pragma unroll
        for (int t = 0; t < 4; t++) {
            const int4* p = (const int4*)(wb + (size_t)(g * 4 + t) * 4096);
            union { int4 q; bf16x8 v; } bh0, bh1, bl0, bl1;
            bh0.q = p[0 * 64 + lane];
            bh1.q = p[1 * 64 + lane];
            bl0.q = p[2 * 64 + lane];
            bl1.q = p[3 * 64 + lane];
            float wsqv = wq[g * 64 + t * 16];
            unsigned sxor = 63u ^ (unsigned)(g * 4 + t);
#pragma unroll
            for (int rt = 0; rt < 2; rt++) {
                f32x4 acc = {0.f, 0.f, 0.f, 0.f};
                acc = __builtin_amdgcn_mfma_f32_16x16x32_bf16(ah[rt][0], bh0.v, acc, 0, 0, 0);
                acc = __builtin_amdgcn_mfma_f32_16x16x32_bf16(ah[rt][1], bh1.v, acc, 0, 0, 0);
                acc = __builtin_amdgcn_mfma_f32_16x16x32_bf16(al[rt][0], bh0.v, acc, 0, 0, 0);
                acc = __builtin_amdgcn_mfma_f32_16x16x32_bf16(al[rt][1], bh1.v, acc, 0, 0, 0);
                acc = __builtin_amdgcn_mfma_f32_16x16x32_bf16(ah[rt][0], bl0.v, acc, 0, 0, 0);
                acc = __builtin_amdgcn_mfma_f32_16x16x32_bf16(ah[rt][1], bl1.v, acc, 0, 0, 0);
#pragma unroll
                for (int r = 0; r < 4; r++) {
                    float c = fmaf(-2.0f, acc[r], wsqv);           // c' = c + 4 > 0
                    unsigned k = (__float_as_uint(c) | 63u) ^ sxor; // low6 = g*4+t
                    int s = rt * 4 + r;
                    unsigned mx = (best_u[s] > k) ? best_u[s] : k;
                    sec_u[s]  = (sec_u[s] < mx) ? sec_u[s] : mx;
                    best_u[s] = (best_u[s] < k) ? best_u[s] : k;
                }
            }
        }
    }

    // decode per-lane winners, then reduce across the 16 columns
    float bval[8], sval[8];
    int bcode[8];
#pragma unroll
    for (int s = 0; s < 8; s++) {
        unsigned k = best_u[s];
        int gt = (int)(k & 63u);
        bcode[s] = kbase + (gt >> 2) * 64 + (gt & 3) * 16 + col;
        bval[s] = __uint_as_float(k & 0xFFFFFFC0u) - C_OFF;
        sval[s] = __uint_as_float(sec_u[s] & 0xFFFFFFC0u) - C_OFF;
    }

#pragma unroll
    for (int m = 1; m < 16; m <<= 1) {
#pragma unroll
        for (int s = 0; s < 8; s++) {
            float ob = __shfl_xor(bval[s], m, 64);
            float os = __shfl_xor(sval[s], m, 64);
            int   oi = __shfl_xor(bcode[s], m, 64);
            float mx = fmaxf(bval[s], ob);
            sval[s] = fminf(fminf(sval[s], os), mx);
            bool take = (ob < bval[s]) || (ob == bval[s] && oi < bcode[s]);
            bval[s] = take ? ob : bval[s];
            bcode[s] = take ? oi : bcode[s];
        }
    }
    if (col == 0) {
        int g4 = lane >> 4;
#pragma unroll
        for (int rt = 0; rt < 2; rt++)
#pragma unroll
            for (int r = 0; r < 4; r++) {
                int row = rbase + rt * 16 + g4 * 4 + r;
                int s = rt * 4 + r;
                unsigned long long key =
                    ((unsigned long long)f2u_ord(bval[s]) << 32) | (unsigned)bcode[s];
                bestk[(size_t)blockIdx.y * N_ROWS + row] = key;
                secd [(size_t)blockIdx.y * N_ROWS + row] = sval[s];
            }
    }
}

// ---------------- kernel 2: merge chunks, flag near-ties ----------------
__global__ __launch_bounds__(256) void vq_merge(const unsigned long long* __restrict__ bestk,
                                                const float* __restrict__ secd,
                                                int* __restrict__ final_idx,
                                                int* __restrict__ recheck_rows,
                                                int* __restrict__ recheck_count) {
    int row = blockIdx.x * 256 + threadIdx.x;

    unsigned long long ks[KSPLIT];
#pragma unroll
    for (int c = 0; c < KSPLIT; c++) ks[c] = bestk[(size_t)c * N_ROWS + row];

    unsigned long long k1 = ks[0];
#pragma unroll
    for (int c = 1; c < KSPLIT; c++) k1 = (ks[c] < k1) ? ks[c] : k1;

    float d1 = u2f_ord((unsigned)(k1 >> 32));
    float d2 = 3.402823466e+38f;
#pragma unroll
    for (int c = 0; c < KSPLIT; c++) {
        if (ks[c] != k1) {
            float bd = u2f_ord((unsigned)(ks[c] >> 32));
            if (bd < d2) d2 = bd;
        }
        float sd = secd[(size_t)c * N_ROWS + row];
        if (sd < d2) d2 = sd;
    }

    final_idx[row] = (int)(k1 & 0xffffffffull);
    if (d2 - d1 < MARGIN) {
        int slot = atomicAdd(recheck_count, 1);
        recheck_rows[slot] = row;
    }
}

// ---------------- kernel 3: np-exact rescan of flagged rows ----------------
__global__ __launch_bounds__(256) void vq_recheck_np(const float* __restrict__ inp,
                                                     const float* __restrict__ weight,
                                                     const float* __restrict__ wsq,
                                                     const int* __restrict__ recheck_rows,
                                                     const int* __restrict__ recheck_count,
                                                     int* __restrict__ final_idx) {
    __shared__ float xs[DIM];
    __shared__ float x2s;
    __shared__ float rd[256];
    __shared__ int   ri[256];
    int tid = threadIdx.x;
    int cnt = *recheck_count;
    if (cnt > N_ROWS) cnt = N_ROWS;

    for (int li = blockIdx.x; li < cnt; li += gridDim.x) {
        int row = recheck_rows[li];
        if (tid < DIM) xs[tid] = inp[(size_t)row * DIM + tid];
        __syncthreads();
        if (tid == 0) x2s = np_pairwise_sq64(xs);
        __syncthreads();
        float x2 = x2s;

        float bd = 3.402823466e+38f;
        int bi = 0x7fffffff;
        for (int code = tid; code < K_CODES; code += 256) {
            const float* wp = weight + (size_t)code * DIM;
            float s = 0.f;
#pragma unroll
            for (int i = 0; i < DIM; i++) s = __builtin_fmaf(xs[i], wp[i], s);
            float t1 = __fadd_rn(x2, wsq[code]);
            float d  = __fsub_rn(t1, __fmul_rn(2.0f, s));
            if (d < bd) { bd = d; bi = code; }
        }
        rd[tid] = bd; ri[tid] = bi;
        __syncthreads();
        for (int s = 128; s > 0; s >>= 1) {
            if (tid < s) {
                if (rd[tid + s] < rd[tid] ||
                    (rd[tid + s] == rd[tid] && ri[tid + s] < ri[tid])) {
                    rd[tid] = rd[tid + s]; ri[tid] = ri[tid + s];
                }
            }
            __syncthreads();
        }
        if (tid == 0) final_idx[row] = ri[0];
        __syncthreads();
    }
}

// ---------------- kernel 4: gather + STE + loss + index write ----------------
__global__ __launch_bounds__(256) void vq_final(const float* __restrict__ inp,
                                                const float* __restrict__ weight,
                                                const int* __restrict__ final_idx,
                                                float* __restrict__ out) {
    int gid = blockIdx.x * 256 + threadIdx.x;
    int row = gid >> 4;
    int sub = gid & 15;

    int idx = final_idx[row];

    float4 x = ((const float4*)inp)[gid];
    float4 w = ((const float4*)weight)[idx * 16 + sub];

    float4 q;
    q.x = x.x + (w.x - x.x);
    q.y = x.y + (w.y - x.y);
    q.z = x.z + (w.z - x.z);
    q.w = x.w + (w.w - x.w);
    ((float4*)(out + OUT_Q))[gid] = q;

    if (sub == 0) out[OUT_IDX + row] = (float)idx;

    float dx = w.x - x.x, dy = w.y - x.y, dz = w.z - x.z, dw = w.w - x.w;
    float lp = dx * dx + dy * dy + dz * dz + dw * dw;

#pragma unroll
    for (int o = 32; o > 0; o >>= 1) lp += __shfl_down(lp, o, 64);

    __shared__ float red[4];
    int wid = threadIdx.x >> 6;
    int lane = threadIdx.x & 63;
    if (lane == 0) red[wid] = lp;
    __syncthreads();
    if (threadIdx.x == 0) {
        float bs = red[0] + red[1] + red[2] + red[3];
        atomicAdd(out + OUT_LOSS, bs * (0.25f / 2097152.f));
    }
}

extern "C" void kernel_launch(void* const* d_in, const int* in_sizes, int n_in,
                              void* d_out, int out_size, void* d_ws, size_t ws_size,
                              hipStream_t stream) {
    const float* inp = (const float*)d_in[0];
    const float* weight = (const float*)d_in[1];
    float* out = (float*)d_out;

    char* ws = (char*)d_ws;
    unsigned long long* bestk = (unsigned long long*)ws;              // 2 MB
    float* secd      = (float*)(ws + (size_t)KSPLIT * N_ROWS * 8);    // 1 MB
    char*  p         = ws + (size_t)KSPLIT * N_ROWS * 12;
    int*   final_idx = (int*)p;                                       // 128 KB
    int*   rrows     = (int*)(p + (size_t)N_ROWS * 4);                // 128 KB
    int*   rcount    = (int*)(p + (size_t)N_ROWS * 8);                // 256 B
    float* wsq       = (float*)(p + (size_t)N_ROWS * 8 + 256);        // 32 KB
    float* wsqC      = (float*)(p + (size_t)N_ROWS * 8 + 256 + 32768);// 32 KB
    int4*  packedW   = (int4*)(p + (size_t)N_ROWS * 8 + 256 + 65536); // 2 MB

    hipMemsetAsync(rcount, 0, sizeof(int), stream);
    hipMemsetAsync(out + OUT_LOSS, 0, sizeof(float), stream);

    vq_prep<<<128, 256, 0, stream>>>(weight, wsq, wsqC, packedW);
    vq_argmin_mfma<<<dim3(N_ROWS / 128, KSPLIT), 256, 0, stream>>>(inp, packedW, wsqC, bestk, secd);
    vq_merge<<<N_ROWS / 256, 256, 0, stream>>>(bestk, secd, final_idx, rrows, rcount);
    vq_recheck_np<<<256, 256, 0, stream>>>(inp, weight, wsq, rrows, rcount, final_idx);
    vq_final<<<(N_ROWS * DIM / 4) / 256, 256, 0, stream>>>(inp, weight, final_idx, out);
}